// Round 4
// baseline (112.481 us; speedup 1.0000x reference)
//
#include <hip/hip_runtime.h>

#define Bn 8
#define Sn 2048
#define Cn 768
#define Hn 64
#define BS (Bn * Sn)

typedef __attribute__((ext_vector_type(8))) short bf16x8;
typedef __attribute__((ext_vector_type(4))) float f32x4;

__device__ __forceinline__ unsigned short f2bf(float x) {
  unsigned int u = __builtin_bit_cast(unsigned int, x);
  u += 0x7FFFu + ((u >> 16) & 1u);
  return (unsigned short)(u >> 16);
}

// ---------------- kernel 0: W convert + transpose: W[c][h] f32 -> Wt[h][c] bf16 ----------------
__global__ __launch_bounds__(256) void wconv(const float* __restrict__ Wq,
                                             const float* __restrict__ Wk,
                                             const float* __restrict__ Wv,
                                             unsigned short* __restrict__ Wt) {
  int idx = blockIdx.x * 256 + threadIdx.x;      // 3*768*64 = 147456 total
  int mat = idx / (Cn * Hn);
  int rem = idx - mat * (Cn * Hn);
  int c = rem / Hn, h = rem - c * Hn;
  const float* W = (mat == 0) ? Wq : (mat == 1) ? Wk : Wv;
  Wt[mat * (Hn * Cn) + h * Cn + c] = f2bf(W[rem]);
}

// ---------------- kernel 1: projections, barrier-free 1-wave blocks ----------------
// Each block = 1 wave = 16 rows x 64 cols, full K=768. No LDS, no __syncthreads.
// X: per-lane stream from global (depth-2 reg prefetch). W: per-lane fragments from
// global Wt (L2-hot broadcast, 96KB/mat), depth-2 prefetch. 3072 independent waves.
__global__ __launch_bounds__(64, 3) void proj(const float* __restrict__ q,
                                              const float* __restrict__ k,
                                              const float* __restrict__ v,
                                              const float* __restrict__ bq,
                                              const float* __restrict__ bk,
                                              const float* __restrict__ bv,
                                              const unsigned short* __restrict__ Wt,
                                              unsigned short* __restrict__ qi,
                                              unsigned short* __restrict__ ki,
                                              unsigned short* __restrict__ vi) {
  const int bid  = blockIdx.x;
  const int mat  = bid >> 10;                 // 1024 row-tiles per matrix
  const int row0 = (bid & 1023) * 16;
  const float* X    = (mat == 0) ? q  : (mat == 1) ? k  : v;
  const float* bias = (mat == 0) ? bq : (mat == 1) ? bk : bv;
  unsigned short* Y = (mat == 0) ? qi : (mat == 1) ? ki : vi;
  const unsigned short* Wm = Wt + mat * (Hn * Cn);
  const float scale = (mat == 0) ? 0.03608439182435161f : 1.0f;  // 1/sqrt(768) folded into qi

  const int lane = threadIdx.x & 63;
  const int col  = lane & 15;
  const int grp  = lane >> 4;

  const float* Xrow = X + (size_t)(row0 + col) * Cn + grp * 8;

  // per-lane W fragment base: frag (nf, ks) at chunk c lives at
  //   Wm + (nf*16+col)*Cn + c*64 + ks*32 + grp*8   (16 bytes)
  const unsigned short* Wl = Wm + (size_t)col * Cn + grp * 8;

  // depth-2 double buffers (all indices compile-time after full unroll)
  float4 ax[2][2][2];   // [buf][ks][piece]
  bf16x8 bw[2][8];      // [buf][nf*2+ks]

#pragma unroll
  for (int d = 0; d < 2; ++d) {
#pragma unroll
    for (int ks = 0; ks < 2; ++ks) {
      ax[d][ks][0] = *(const float4*)(Xrow + d * 64 + ks * 32);
      ax[d][ks][1] = *(const float4*)(Xrow + d * 64 + ks * 32 + 4);
    }
#pragma unroll
    for (int nf = 0; nf < 4; ++nf)
#pragma unroll
      for (int ks = 0; ks < 2; ++ks)
        bw[d][nf * 2 + ks] =
            *(const bf16x8*)(Wl + (size_t)(nf * 16) * Cn + d * 64 + ks * 32);
  }

  f32x4 acc[4] = {};

#pragma unroll
  for (int c = 0; c < 12; ++c) {
    const int buf = c & 1;
    // convert A fragments (loads for this buf issued 2 iters ago)
    bf16x8 av[2];
#pragma unroll
    for (int ks = 0; ks < 2; ++ks) {
      const float4 p0 = ax[buf][ks][0], p1 = ax[buf][ks][1];
      av[ks][0] = (short)f2bf(p0.x); av[ks][1] = (short)f2bf(p0.y);
      av[ks][2] = (short)f2bf(p0.z); av[ks][3] = (short)f2bf(p0.w);
      av[ks][4] = (short)f2bf(p1.x); av[ks][5] = (short)f2bf(p1.y);
      av[ks][6] = (short)f2bf(p1.z); av[ks][7] = (short)f2bf(p1.w);
    }
    bf16x8 bv0[8];
#pragma unroll
    for (int i = 0; i < 8; ++i) bv0[i] = bw[buf][i];
    // refill this buf with chunk c+2 (issue before MFMAs so latency hides under them)
    if (c < 10) {
#pragma unroll
      for (int ks = 0; ks < 2; ++ks) {
        ax[buf][ks][0] = *(const float4*)(Xrow + (c + 2) * 64 + ks * 32);
        ax[buf][ks][1] = *(const float4*)(Xrow + (c + 2) * 64 + ks * 32 + 4);
      }
#pragma unroll
      for (int nf = 0; nf < 4; ++nf)
#pragma unroll
        for (int ks = 0; ks < 2; ++ks)
          bw[buf][nf * 2 + ks] =
              *(const bf16x8*)(Wl + (size_t)(nf * 16) * Cn + (c + 2) * 64 + ks * 32);
    }
    // 8 MFMAs
#pragma unroll
    for (int ks = 0; ks < 2; ++ks)
#pragma unroll
      for (int nf = 0; nf < 4; ++nf)
        acc[nf] = __builtin_amdgcn_mfma_f32_16x16x32_bf16(av[ks], bv0[nf * 2 + ks], acc[nf], 0, 0, 0);
  }

  // epilogue: D layout col = lane&15, row = grp*4 + reg
#pragma unroll
  for (int nf = 0; nf < 4; ++nf) {
    int h = nf * 16 + col;
    float bb = bias[h];
#pragma unroll
    for (int r2 = 0; r2 < 4; ++r2) {
      int row = row0 + grp * 4 + r2;
      Y[(size_t)row * Hn + h] = f2bf((acc[nf][r2] + bb) * scale);
    }
  }
}

// ---------------- kernel 2: flash attention, optional KV split ----------------
template <int SPLIT>
__global__ __launch_bounds__(256) void attn(const unsigned short* __restrict__ qi,
                                            const unsigned short* __restrict__ ki,
                                            const unsigned short* __restrict__ vi,
                                            float* __restrict__ pacc,
                                            float* __restrict__ pm,
                                            float* __restrict__ pl,
                                            float* __restrict__ out,
                                            int tpb) {
  const int bq    = blockIdx.x & 255;
  const int split = blockIdx.x >> 8;
  const int b  = bq >> 5;
  const int s0 = (bq & 31) * 64;
  const int t0 = split * tpb;
  const unsigned short* Qb = qi + ((size_t)b * Sn + s0) * Hn;
  const unsigned short* Kb = ki + (size_t)b * Sn * Hn;
  const unsigned short* Vb = vi + (size_t)b * Sn * Hn;

  __shared__ __align__(16) unsigned char Ks[64 * 128];       // [key][dim] bf16, swizzled
  __shared__ __align__(16) unsigned char Vt[64 * 128];       // [dim][key] bf16, swizzled
  __shared__ __align__(16) unsigned char Ps[4 * 16 * 128];   // per-wave [16 q][64 key] bf16

  const int tid  = threadIdx.x;
  const int lane = tid & 63;
  const int w    = tid >> 6;
  const int col  = lane & 15;
  const int grp  = lane >> 4;

  bf16x8 qa[2];
#pragma unroll
  for (int ks2 = 0; ks2 < 2; ++ks2)
    qa[ks2] = *(const bf16x8*)(Qb + (size_t)(w * 16 + col) * Hn + ks2 * 32 + grp * 8);

  f32x4 acc[4] = {};
  float m[4], l[4];
#pragma unroll
  for (int r = 0; r < 4; ++r) { m[r] = -1e30f; l[r] = 0.0f; }

  for (int t = t0; t < t0 + tpb; ++t) {
    const unsigned short* Kt = Kb + t * 64 * Hn;
    const unsigned short* Vg = Vb + t * 64 * Hn;
    __syncthreads();  // previous tile fully consumed by all waves
    {
      int kr = tid >> 2, p = tid & 3;
      const uint4* src = (const uint4*)(Kt + kr * Hn);
      uint4 a  = src[p * 2];
      uint4 b2 = src[p * 2 + 1];
      *(uint4*)(Ks + kr * 128 + ((p * 32) ^ ((kr & 7) << 4)))        = a;
      *(uint4*)(Ks + kr * 128 + (((p * 32) + 16) ^ ((kr & 7) << 4))) = b2;
    }
    {
      int kp = tid >> 3;
      int dg = tid & 7;
      uint4 v0 = *(const uint4*)(Vg + (2 * kp) * Hn + dg * 8);
      uint4 v1 = *(const uint4*)(Vg + (2 * kp + 1) * Hn + dg * 8);
      const unsigned short* a0 = (const unsigned short*)&v0;
      const unsigned short* a1 = (const unsigned short*)&v1;
#pragma unroll
      for (int j0 = 0; j0 < 8; ++j0) {
        int j = (j0 + dg) & 7;
        int d = dg * 8 + j;
        unsigned int pk = (unsigned int)a0[j] | ((unsigned int)a1[j] << 16);
        *(unsigned int*)(Vt + d * 128 + ((4 * kp) ^ ((d & 7) << 4))) = pk;
      }
    }
    __syncthreads();
    // S = Q K^T
    f32x4 sf[4] = {};
#pragma unroll
    for (int ks2 = 0; ks2 < 2; ++ks2) {
#pragma unroll
      for (int nf = 0; nf < 4; ++nf) {
        int kr = nf * 16 + col;
        bf16x8 bfr = *(const bf16x8*)(Ks + kr * 128 + ((ks2 * 64 + grp * 16) ^ ((kr & 7) << 4)));
        sf[nf] = __builtin_amdgcn_mfma_f32_16x16x32_bf16(qa[ks2], bfr, sf[nf], 0, 0, 0);
      }
    }
    // online softmax
    float mn[4], fs[4];
#pragma unroll
    for (int r = 0; r < 4; ++r) {
      float mx = fmaxf(fmaxf(sf[0][r], sf[1][r]), fmaxf(sf[2][r], sf[3][r]));
#pragma unroll
      for (int off = 1; off < 16; off <<= 1)
        mx = fmaxf(mx, __shfl_xor(mx, off, 64));
      mn[r] = fmaxf(m[r], mx);
      fs[r] = __expf(m[r] - mn[r]);
      m[r]  = mn[r];
    }
#pragma unroll
    for (int nf = 0; nf < 4; ++nf)
#pragma unroll
      for (int r = 0; r < 4; ++r)
        sf[nf][r] = __expf(sf[nf][r] - mn[r]);
#pragma unroll
    for (int r = 0; r < 4; ++r) {
      float sm = sf[0][r] + sf[1][r] + sf[2][r] + sf[3][r];
#pragma unroll
      for (int off = 1; off < 16; off <<= 1)
        sm += __shfl_xor(sm, off, 64);
      l[r] = l[r] * fs[r] + sm;
    }
#pragma unroll
    for (int nf = 0; nf < 4; ++nf) {
#pragma unroll
      for (int r = 0; r < 4; ++r) {
        acc[nf][r] *= fs[r];
        int prow = grp * 4 + r;
        int key  = nf * 16 + col;
        *(unsigned short*)(Ps + w * 2048 + prow * 128 + ((key * 2) ^ ((prow & 7) << 4))) =
            f2bf(sf[nf][r]);
      }
    }
    // per-wave Ps: no cross-wave barrier needed before PV
#pragma unroll
    for (int kk = 0; kk < 2; ++kk) {
      bf16x8 pa = *(const bf16x8*)(Ps + w * 2048 + col * 128 +
                                   ((kk * 64 + grp * 16) ^ ((col & 7) << 4)));
#pragma unroll
      for (int nf = 0; nf < 4; ++nf) {
        int dr = nf * 16 + col;
        bf16x8 bv = *(const bf16x8*)(Vt + dr * 128 + ((kk * 64 + grp * 16) ^ ((dr & 7) << 4)));
        acc[nf] = __builtin_amdgcn_mfma_f32_16x16x32_bf16(pa, bv, acc[nf], 0, 0, 0);
      }
    }
  }
  // epilogue
  if (SPLIT) {
    const size_t sb = (size_t)split * BS + (size_t)b * Sn;
#pragma unroll
    for (int nf = 0; nf < 4; ++nf) {
#pragma unroll
      for (int r = 0; r < 4; ++r) {
        int row = s0 + w * 16 + grp * 4 + r;
        pacc[(sb + row) * Hn + nf * 16 + col] = acc[nf][r];
      }
    }
    if (col == 0) {
#pragma unroll
      for (int r = 0; r < 4; ++r) {
        int row = s0 + w * 16 + grp * 4 + r;
        pm[sb + row] = m[r];
        pl[sb + row] = l[r];
      }
    }
  } else {
#pragma unroll
    for (int nf = 0; nf < 4; ++nf) {
#pragma unroll
      for (int r = 0; r < 4; ++r) {
        int row = s0 + w * 16 + grp * 4 + r;
        out[((size_t)b * Sn + row) * Hn + nf * 16 + col] = acc[nf][r] / l[r];
      }
    }
  }
}

// ---------------- kernel 3: combine split partials ----------------
__global__ __launch_bounds__(256) void combine(const float* __restrict__ pacc,
                                               const float* __restrict__ pm,
                                               const float* __restrict__ pl,
                                               float* __restrict__ out,
                                               int nsplit) {
  int gid = blockIdx.x * 256 + threadIdx.x;
  int gr  = gid >> 4;          // global row in [0, B*S)
  int dq  = (gid & 15) * 4;    // dim quad
  float M = -1e30f;
  for (int s = 0; s < nsplit; ++s) M = fmaxf(M, pm[(size_t)s * BS + gr]);
  float L = 0.0f;
  float4 o = make_float4(0.f, 0.f, 0.f, 0.f);
  for (int s = 0; s < nsplit; ++s) {
    float wgt = __expf(pm[(size_t)s * BS + gr] - M);
    L += pl[(size_t)s * BS + gr] * wgt;
    float4 p = *(const float4*)(pacc + ((size_t)s * BS + gr) * Hn + dq);
    o.x += p.x * wgt; o.y += p.y * wgt; o.z += p.z * wgt; o.w += p.w * wgt;
  }
  float inv = 1.0f / L;
  float4 r = make_float4(o.x * inv, o.y * inv, o.z * inv, o.w * inv);
  *(float4*)(out + (size_t)gr * Hn + dq) = r;
}

extern "C" void kernel_launch(void* const* d_in, const int* in_sizes, int n_in,
                              void* d_out, int out_size, void* d_ws, size_t ws_size,
                              hipStream_t stream) {
  const float* q  = (const float*)d_in[0];
  const float* k  = (const float*)d_in[1];
  const float* v  = (const float*)d_in[2];
  const float* Wq = (const float*)d_in[3];
  const float* bq = (const float*)d_in[4];
  const float* Wk = (const float*)d_in[5];
  const float* bk = (const float*)d_in[6];
  const float* Wv = (const float*)d_in[7];
  const float* bv = (const float*)d_in[8];
  float* out = (float*)d_out;

  unsigned short* Wt = (unsigned short*)d_ws;            // [3][64][768] bf16
  unsigned short* qi = Wt + 3 * Hn * Cn;                 // bf16, pre-scaled by 1/sqrt(C)
  unsigned short* ki = qi + (size_t)BS * Hn;
  unsigned short* vi = ki + (size_t)BS * Hn;
  float* pacc = (float*)(vi + (size_t)BS * Hn);

  const size_t base_bytes = (size_t)(3 * Hn * Cn + 3 * (size_t)BS * Hn) * 2;
  int nsplit = 4;
  while (nsplit > 1 &&
         base_bytes + (size_t)nsplit * ((size_t)BS * Hn * 4 + 2 * (size_t)BS * 4) > ws_size)
    nsplit >>= 1;
  bool direct = (base_bytes + (size_t)nsplit * ((size_t)BS * Hn * 4 + 2 * (size_t)BS * 4) > ws_size);

  float* pm = pacc + (size_t)nsplit * BS * Hn;
  float* pl = pm + (size_t)nsplit * BS;

  wconv<<<dim3((3 * Cn * Hn) / 256), dim3(256), 0, stream>>>(Wq, Wk, Wv, Wt);
  proj<<<dim3(3 * 1024), dim3(64), 0, stream>>>(q, k, v, bq, bk, bv, Wt, qi, ki, vi);
  if (direct) {
    attn<0><<<dim3(256), dim3(256), 0, stream>>>(qi, ki, vi, nullptr, nullptr, nullptr, out, 32);
  } else {
    attn<1><<<dim3(256 * nsplit), dim3(256), 0, stream>>>(qi, ki, vi, pacc, pm, pl, nullptr,
                                                          32 / nsplit);
    combine<<<dim3(BS * 16 / 256), dim3(256), 0, stream>>>(pacc, pm, pl, out, nsplit);
  }
}

// Round 5
// 96.121 us; speedup vs baseline: 1.1702x; 1.1702x over previous
//
#include <hip/hip_runtime.h>

#define Bn 8
#define Sn 2048
#define Cn 768
#define Hn 64
#define BS (Bn * Sn)

typedef __attribute__((ext_vector_type(8))) short bf16x8;
typedef __attribute__((ext_vector_type(4))) float f32x4;

__device__ __forceinline__ unsigned short f2bf(float x) {
  unsigned int u = __builtin_bit_cast(unsigned int, x);
  u += 0x7FFFu + ((u >> 16) & 1u);
  return (unsigned short)(u >> 16);
}

// ---------------- kernel 0: W convert + transpose: W[c][h] f32 -> Wt[h][c] bf16 ----------------
__global__ __launch_bounds__(256) void wconv(const float* __restrict__ Wq,
                                             const float* __restrict__ Wk,
                                             const float* __restrict__ Wv,
                                             unsigned short* __restrict__ Wt) {
  int idx = blockIdx.x * 256 + threadIdx.x;      // 3*768*64 = 147456 total
  int mat = idx / (Cn * Hn);
  int rem = idx - mat * (Cn * Hn);
  int c = rem / Hn, h = rem - c * Hn;
  const float* W = (mat == 0) ? Wq : (mat == 1) ? Wk : Wv;
  Wt[mat * (Hn * Cn) + h * Cn + c] = f2bf(W[rem]);
}

// ---------------- kernel 1: projection partial GEMM, K-split ----------------
// grid = 3 * psplit * 256 blocks; block = 64 rows x 64 cols over K-range
// [sp*Cn/psplit, (sp+1)*Cn/psplit). R2's proven staging structure, f32 partial out.
__global__ __launch_bounds__(256) void proj(const float* __restrict__ q,
                                            const float* __restrict__ k,
                                            const float* __restrict__ v,
                                            const unsigned short* __restrict__ Wt,
                                            float* __restrict__ part,
                                            int psplit) {
  const int per_mat = psplit << 8;
  const int mat = blockIdx.x / per_mat;
  const int rem = blockIdx.x - mat * per_mat;
  const int sp  = rem >> 8;
  const int row0 = (rem & 255) * 64;
  const int kb     = sp * (Cn / 2) * (psplit - 1);  // psplit==1 -> 0; ==2 -> sp*384
  const int nchunk = (Cn / 64) / psplit;
  const float* X = (mat == 0) ? q : (mat == 1) ? k : v;
  const unsigned short* Wm = Wt + mat * (Hn * Cn);
  float* P = part + ((size_t)(sp * 3 + mat) * BS + row0) * Hn;

  __shared__ __align__(16) unsigned char Xs[64 * 128];  // [64 rows][64 bf16], xor-swizzled
  __shared__ __align__(16) unsigned char Ws[64 * 128];  // [64 cols][64 bf16], xor-swizzled

  const int tid  = threadIdx.x;
  const int lane = tid & 63;
  const int w    = tid >> 6;
  const int col  = lane & 15;
  const int grp  = lane >> 4;

  f32x4 acc[4] = {};

  for (int c = 0; c < nchunk; ++c) {
    const int k0 = kb + c * 64;
    __syncthreads();
#pragma unroll
    for (int i = 0; i < 4; ++i) {
      int f4 = tid + i * 256;
      int r  = f4 >> 4;
      int c4 = f4 & 15;
      float4 xv = *(const float4*)(X + (size_t)(row0 + r) * Cn + k0 + c4 * 4);
      ushort4 hv;
      hv.x = f2bf(xv.x); hv.y = f2bf(xv.y); hv.z = f2bf(xv.z); hv.w = f2bf(xv.w);
      *(ushort4*)(Xs + r * 128 + ((c4 * 8) ^ ((r & 7) << 4))) = hv;
    }
    {
      int r = tid >> 2;
      int p = tid & 3;
      const uint4* src = (const uint4*)(Wm + (size_t)r * Cn + k0);
      uint4 a  = src[p * 2];
      uint4 b2 = src[p * 2 + 1];
      *(uint4*)(Ws + r * 128 + ((p * 32) ^ ((r & 7) << 4)))        = a;
      *(uint4*)(Ws + r * 128 + (((p * 32) + 16) ^ ((r & 7) << 4))) = b2;
    }
    __syncthreads();
    const int rloc = w * 16 + col;
#pragma unroll
    for (int ks = 0; ks < 2; ++ks) {
      bf16x8 a = *(const bf16x8*)(Xs + rloc * 128 + ((ks * 64 + grp * 16) ^ ((rloc & 7) << 4)));
#pragma unroll
      for (int nf = 0; nf < 4; ++nf) {
        int wr = nf * 16 + col;
        bf16x8 bfr = *(const bf16x8*)(Ws + wr * 128 + ((ks * 64 + grp * 16) ^ ((wr & 7) << 4)));
        acc[nf] = __builtin_amdgcn_mfma_f32_16x16x32_bf16(a, bfr, acc[nf], 0, 0, 0);
      }
    }
  }
  // f32 partial epilogue (bias/scale/cvt deferred to preduce)
#pragma unroll
  for (int nf = 0; nf < 4; ++nf) {
    int h = nf * 16 + col;
#pragma unroll
    for (int r2 = 0; r2 < 4; ++r2) {
      int row = w * 16 + grp * 4 + r2;
      P[(size_t)row * Hn + h] = acc[nf][r2];
    }
  }
}

// ---------------- kernel 1b: reduce K-split partials + bias (+scale for q) -> bf16 ----------------
// thread = (mat, row, dim-quad); grid = 3*BS*16/256 = 3072 blocks
__global__ __launch_bounds__(256) void preduce(const float* __restrict__ part,
                                               const float* __restrict__ bq,
                                               const float* __restrict__ bk,
                                               const float* __restrict__ bv,
                                               unsigned short* __restrict__ qi,
                                               unsigned short* __restrict__ ki,
                                               unsigned short* __restrict__ vi,
                                               int psplit) {
  int gid = blockIdx.x * 256 + threadIdx.x;
  int mat = gid / (BS * 16);
  int rem = gid - mat * (BS * 16);
  int row = rem >> 4;
  int dq  = (rem & 15) * 4;
  float4 s = *(const float4*)(part + ((size_t)mat * BS + row) * Hn + dq);
  if (psplit == 2) {
    float4 t = *(const float4*)(part + ((size_t)(3 + mat) * BS + row) * Hn + dq);
    s.x += t.x; s.y += t.y; s.z += t.z; s.w += t.w;
  }
  const float* bias = (mat == 0) ? bq : (mat == 1) ? bk : bv;
  unsigned short* Y = (mat == 0) ? qi : (mat == 1) ? ki : vi;
  float4 bb = *(const float4*)(bias + dq);
  float sc = (mat == 0) ? 0.03608439182435161f : 1.0f;  // 1/sqrt(768) folded into qi
  ushort4 o;
  o.x = f2bf((s.x + bb.x) * sc);
  o.y = f2bf((s.y + bb.y) * sc);
  o.z = f2bf((s.z + bb.z) * sc);
  o.w = f2bf((s.w + bb.w) * sc);
  *(ushort4*)(Y + (size_t)row * Hn + dq) = o;
}

// ---------------- kernel 2: flash attention, optional KV split ----------------
template <int SPLIT>
__global__ __launch_bounds__(256) void attn(const unsigned short* __restrict__ qi,
                                            const unsigned short* __restrict__ ki,
                                            const unsigned short* __restrict__ vi,
                                            float* __restrict__ pacc,
                                            float* __restrict__ pm,
                                            float* __restrict__ pl,
                                            float* __restrict__ out,
                                            int tpb) {
  const int bq    = blockIdx.x & 255;
  const int split = blockIdx.x >> 8;
  const int b  = bq >> 5;
  const int s0 = (bq & 31) * 64;
  const int t0 = split * tpb;
  const unsigned short* Qb = qi + ((size_t)b * Sn + s0) * Hn;
  const unsigned short* Kb = ki + (size_t)b * Sn * Hn;
  const unsigned short* Vb = vi + (size_t)b * Sn * Hn;

  __shared__ __align__(16) unsigned char Ks[64 * 128];       // [key][dim] bf16, swizzled
  __shared__ __align__(16) unsigned char Vt[64 * 128];       // [dim][key] bf16, swizzled
  __shared__ __align__(16) unsigned char Ps[4 * 16 * 128];   // per-wave [16 q][64 key] bf16

  const int tid  = threadIdx.x;
  const int lane = tid & 63;
  const int w    = tid >> 6;
  const int col  = lane & 15;
  const int grp  = lane >> 4;

  bf16x8 qa[2];
#pragma unroll
  for (int ks2 = 0; ks2 < 2; ++ks2)
    qa[ks2] = *(const bf16x8*)(Qb + (size_t)(w * 16 + col) * Hn + ks2 * 32 + grp * 8);

  f32x4 acc[4] = {};
  float m[4], l[4];
#pragma unroll
  for (int r = 0; r < 4; ++r) { m[r] = -1e30f; l[r] = 0.0f; }

  for (int t = t0; t < t0 + tpb; ++t) {
    const unsigned short* Kt = Kb + t * 64 * Hn;
    const unsigned short* Vg = Vb + t * 64 * Hn;
    __syncthreads();  // previous tile fully consumed by all waves
    {
      int kr = tid >> 2, p = tid & 3;
      const uint4* src = (const uint4*)(Kt + kr * Hn);
      uint4 a  = src[p * 2];
      uint4 b2 = src[p * 2 + 1];
      *(uint4*)(Ks + kr * 128 + ((p * 32) ^ ((kr & 7) << 4)))        = a;
      *(uint4*)(Ks + kr * 128 + (((p * 32) + 16) ^ ((kr & 7) << 4))) = b2;
    }
    {
      int kp = tid >> 3;
      int dg = tid & 7;
      uint4 v0 = *(const uint4*)(Vg + (2 * kp) * Hn + dg * 8);
      uint4 v1 = *(const uint4*)(Vg + (2 * kp + 1) * Hn + dg * 8);
      const unsigned short* a0 = (const unsigned short*)&v0;
      const unsigned short* a1 = (const unsigned short*)&v1;
#pragma unroll
      for (int j0 = 0; j0 < 8; ++j0) {
        int j = (j0 + dg) & 7;
        int d = dg * 8 + j;
        unsigned int pk = (unsigned int)a0[j] | ((unsigned int)a1[j] << 16);
        *(unsigned int*)(Vt + d * 128 + ((4 * kp) ^ ((d & 7) << 4))) = pk;
      }
    }
    __syncthreads();
    // S = Q K^T
    f32x4 sf[4] = {};
#pragma unroll
    for (int ks2 = 0; ks2 < 2; ++ks2) {
#pragma unroll
      for (int nf = 0; nf < 4; ++nf) {
        int kr = nf * 16 + col;
        bf16x8 bfr = *(const bf16x8*)(Ks + kr * 128 + ((ks2 * 64 + grp * 16) ^ ((kr & 7) << 4)));
        sf[nf] = __builtin_amdgcn_mfma_f32_16x16x32_bf16(qa[ks2], bfr, sf[nf], 0, 0, 0);
      }
    }
    // online softmax
    float mn[4], fs[4];
#pragma unroll
    for (int r = 0; r < 4; ++r) {
      float mx = fmaxf(fmaxf(sf[0][r], sf[1][r]), fmaxf(sf[2][r], sf[3][r]));
#pragma unroll
      for (int off = 1; off < 16; off <<= 1)
        mx = fmaxf(mx, __shfl_xor(mx, off, 64));
      mn[r] = fmaxf(m[r], mx);
      fs[r] = __expf(m[r] - mn[r]);
      m[r]  = mn[r];
    }
#pragma unroll
    for (int nf = 0; nf < 4; ++nf)
#pragma unroll
      for (int r = 0; r < 4; ++r)
        sf[nf][r] = __expf(sf[nf][r] - mn[r]);
#pragma unroll
    for (int r = 0; r < 4; ++r) {
      float sm = sf[0][r] + sf[1][r] + sf[2][r] + sf[3][r];
#pragma unroll
      for (int off = 1; off < 16; off <<= 1)
        sm += __shfl_xor(sm, off, 64);
      l[r] = l[r] * fs[r] + sm;
    }
#pragma unroll
    for (int nf = 0; nf < 4; ++nf) {
#pragma unroll
      for (int r = 0; r < 4; ++r) {
        acc[nf][r] *= fs[r];
        int prow = grp * 4 + r;
        int key  = nf * 16 + col;
        *(unsigned short*)(Ps + w * 2048 + prow * 128 + ((key * 2) ^ ((prow & 7) << 4))) =
            f2bf(sf[nf][r]);
      }
    }
    // per-wave Ps: no cross-wave barrier needed before PV
#pragma unroll
    for (int kk = 0; kk < 2; ++kk) {
      bf16x8 pa = *(const bf16x8*)(Ps + w * 2048 + col * 128 +
                                   ((kk * 64 + grp * 16) ^ ((col & 7) << 4)));
#pragma unroll
      for (int nf = 0; nf < 4; ++nf) {
        int dr = nf * 16 + col;
        bf16x8 bv = *(const bf16x8*)(Vt + dr * 128 + ((kk * 64 + grp * 16) ^ ((dr & 7) << 4)));
        acc[nf] = __builtin_amdgcn_mfma_f32_16x16x32_bf16(pa, bv, acc[nf], 0, 0, 0);
      }
    }
  }
  // epilogue
  if (SPLIT) {
    const size_t sb = (size_t)split * BS + (size_t)b * Sn;
#pragma unroll
    for (int nf = 0; nf < 4; ++nf) {
#pragma unroll
      for (int r = 0; r < 4; ++r) {
        int row = s0 + w * 16 + grp * 4 + r;
        pacc[(sb + row) * Hn + nf * 16 + col] = acc[nf][r];
      }
    }
    if (col == 0) {
#pragma unroll
      for (int r = 0; r < 4; ++r) {
        int row = s0 + w * 16 + grp * 4 + r;
        pm[sb + row] = m[r];
        pl[sb + row] = l[r];
      }
    }
  } else {
#pragma unroll
    for (int nf = 0; nf < 4; ++nf) {
#pragma unroll
      for (int r = 0; r < 4; ++r) {
        int row = s0 + w * 16 + grp * 4 + r;
        out[((size_t)b * Sn + row) * Hn + nf * 16 + col] = acc[nf][r] / l[r];
      }
    }
  }
}

// ---------------- kernel 3: combine attn split partials ----------------
__global__ __launch_bounds__(256) void combine(const float* __restrict__ pacc,
                                               const float* __restrict__ pm,
                                               const float* __restrict__ pl,
                                               float* __restrict__ out,
                                               int nsplit) {
  int gid = blockIdx.x * 256 + threadIdx.x;
  int gr  = gid >> 4;          // global row in [0, B*S)
  int dq  = (gid & 15) * 4;    // dim quad
  float M = -1e30f;
  for (int s = 0; s < nsplit; ++s) M = fmaxf(M, pm[(size_t)s * BS + gr]);
  float L = 0.0f;
  float4 o = make_float4(0.f, 0.f, 0.f, 0.f);
  for (int s = 0; s < nsplit; ++s) {
    float wgt = __expf(pm[(size_t)s * BS + gr] - M);
    L += pl[(size_t)s * BS + gr] * wgt;
    float4 p = *(const float4*)(pacc + ((size_t)s * BS + gr) * Hn + dq);
    o.x += p.x * wgt; o.y += p.y * wgt; o.z += p.z * wgt; o.w += p.w * wgt;
  }
  float inv = 1.0f / L;
  float4 r = make_float4(o.x * inv, o.y * inv, o.z * inv, o.w * inv);
  *(float4*)(out + (size_t)gr * Hn + dq) = r;
}

extern "C" void kernel_launch(void* const* d_in, const int* in_sizes, int n_in,
                              void* d_out, int out_size, void* d_ws, size_t ws_size,
                              hipStream_t stream) {
  const float* q  = (const float*)d_in[0];
  const float* k  = (const float*)d_in[1];
  const float* v  = (const float*)d_in[2];
  const float* Wq = (const float*)d_in[3];
  const float* bq = (const float*)d_in[4];
  const float* Wk = (const float*)d_in[5];
  const float* bk = (const float*)d_in[6];
  const float* Wv = (const float*)d_in[7];
  const float* bv = (const float*)d_in[8];
  float* out = (float*)d_out;

  unsigned short* Wt = (unsigned short*)d_ws;            // [3][64][768] bf16
  unsigned short* qi = Wt + 3 * Hn * Cn;                 // bf16, pre-scaled by 1/sqrt(C)
  unsigned short* ki = qi + (size_t)BS * Hn;
  unsigned short* vi = ki + (size_t)BS * Hn;
  // shared scratch region: proj partials (dead before attn runs) overlaps attn partials
  float* shared_f = (float*)(vi + (size_t)BS * Hn);

  const size_t base_bytes = (size_t)(3 * Hn * Cn + 3 * (size_t)BS * Hn) * 2;
  const size_t avail = (ws_size > base_bytes) ? ws_size - base_bytes : 0;

  // proj K-split: 2 if partials fit, else 1 (partials then = plain f32 Y)
  const size_t proj_part_bytes = (size_t)3 * BS * Hn * 4;   // per split
  int psplit = (avail >= 2 * proj_part_bytes) ? 2 : 1;

  // attn KV-split
  int nsplit = 4;
  while (nsplit > 1 &&
         (size_t)nsplit * ((size_t)BS * Hn * 4 + 2 * (size_t)BS * 4) > avail)
    nsplit >>= 1;
  bool direct = ((size_t)nsplit * ((size_t)BS * Hn * 4 + 2 * (size_t)BS * 4) > avail);

  float* ppart = shared_f;                       // [psplit][3][BS][Hn] f32
  float* pacc  = shared_f;                       // [nsplit][BS][Hn] f32 (after preduce)
  float* pm    = pacc + (size_t)nsplit * BS * Hn;
  float* pl    = pm + (size_t)nsplit * BS;

  wconv<<<dim3((3 * Cn * Hn) / 256), dim3(256), 0, stream>>>(Wq, Wk, Wv, Wt);
  proj<<<dim3(3 * psplit * 256), dim3(256), 0, stream>>>(q, k, v, Wt, ppart, psplit);
  preduce<<<dim3(3 * BS * 16 / 256), dim3(256), 0, stream>>>(ppart, bq, bk, bv, qi, ki, vi,
                                                             psplit);
  if (direct) {
    attn<0><<<dim3(256), dim3(256), 0, stream>>>(qi, ki, vi, nullptr, nullptr, nullptr, out, 32);
  } else {
    attn<1><<<dim3(256 * nsplit), dim3(256), 0, stream>>>(qi, ki, vi, pacc, pm, pl, nullptr,
                                                          32 / nsplit);
    combine<<<dim3(BS * 16 / 256), dim3(256), 0, stream>>>(pacc, pm, pl, out, nsplit);
  }
}